// Round 1
// baseline (1813.075 us; speedup 1.0000x reference)
//
#include <hip/hip_runtime.h>

#define SLEN 2048
#define DM   2048
#define NH   16
#define NKVH 4
#define HD   128
#define KVD  512
#define FF   8192
#define NLAYER 2
#define EPSV 1e-5f

typedef unsigned short bhalf;
typedef __attribute__((__ext_vector_type__(8))) __bf16 bf16x8;
typedef __attribute__((__ext_vector_type__(4))) float f32x4;

__device__ __forceinline__ float b2f(bhalf u) {
  union { unsigned int i; float f; } v; v.i = ((unsigned int)u) << 16; return v.f;
}
__device__ __forceinline__ bhalf f2b(float f) {
  unsigned int x = __float_as_uint(f);
  return (bhalf)((x + 0x7fffu + ((x >> 16) & 1u)) >> 16);  // RNE
}

typedef __attribute__((address_space(1))) const void gas_cvoid;
typedef __attribute__((address_space(3))) void las_void;
__device__ __forceinline__ void gload16(const void* g, void* l) {
  __builtin_amdgcn_global_load_lds((gas_cvoid*)g, (las_void*)l, 16, 0, 0);
}
__device__ __forceinline__ f32x4 mfma16(bf16x8 a, bf16x8 b, f32x4 c) {
  return __builtin_amdgcn_mfma_f32_16x16x32_bf16(a, b, c, 0, 0, 0);
}

// ---------------- f32 -> bf16 convert ----------------
__global__ __launch_bounds__(256)
void cvt_f32_bf16(const float* __restrict__ in, bhalf* __restrict__ out, size_t n) {
  size_t i = ((size_t)blockIdx.x * 256 + threadIdx.x) * 8;
  const size_t stride = (size_t)gridDim.x * 256 * 8;
  for (; i < n; i += stride) {
    float4 a = *(const float4*)(in + i);
    float4 b = *(const float4*)(in + i + 4);
    int4 o; bhalf* t = (bhalf*)&o;
    t[0]=f2b(a.x); t[1]=f2b(a.y); t[2]=f2b(a.z); t[3]=f2b(a.w);
    t[4]=f2b(b.x); t[5]=f2b(b.y); t[6]=f2b(b.z); t[7]=f2b(b.w);
    *(int4*)(out + i) = o;
  }
}

// ---------------- RMSNorm: f32 in -> bf16 out ----------------
__global__ __launch_bounds__(256)
void rmsnorm_k(const float* __restrict__ x, const float* __restrict__ w,
               bhalf* __restrict__ out) {
  const int row = blockIdx.x;
  const int tid = threadIdx.x;
  const float4* xr = (const float4*)(x + (size_t)row * DM);
  float4 a = xr[tid*2], b = xr[tid*2 + 1];
  float ss = a.x*a.x + a.y*a.y + a.z*a.z + a.w*a.w
           + b.x*b.x + b.y*b.y + b.z*b.z + b.w*b.w;
  #pragma unroll
  for (int off = 32; off > 0; off >>= 1) ss += __shfl_down(ss, off);
  __shared__ float red[5];
  const int wv = tid >> 6, l = tid & 63;
  if (l == 0) red[wv] = ss;
  __syncthreads();
  if (tid == 0) red[4] = rsqrtf((red[0]+red[1]+red[2]+red[3]) * (1.0f/DM) + EPSV);
  __syncthreads();
  const float rs = red[4];
  const float* wp = w + tid*8;
  float vals[8] = {a.x,a.y,a.z,a.w,b.x,b.y,b.z,b.w};
  int4 o; bhalf* t = (bhalf*)&o;
  #pragma unroll
  for (int j = 0; j < 8; ++j) t[j] = f2b(vals[j] * rs * wp[j]);
  *(int4*)(out + (size_t)row*DM + tid*8) = o;
}

// ---------------- RoPE (in-place on bf16, pairs along last dim) ----------------
__global__ __launch_bounds__(256)
void rope_k(bhalf* __restrict__ t, const float* __restrict__ c,
            const float* __restrict__ s, int nheads) {
  const int idx = blockIdx.x * 256 + threadIdx.x;  // s*nheads*64 exact
  const int j  = idx & 63;
  const int hh = (idx >> 6) % nheads;
  const int sp = idx / (nheads * 64);
  const float cv = c[sp*64 + j], sv = s[sp*64 + j];
  unsigned int* p = (unsigned int*)(t + ((size_t)sp*nheads + hh)*HD + 2*j);
  const unsigned int pv = *p;
  const float t0 = b2f((bhalf)(pv & 0xffffu)), t1 = b2f((bhalf)(pv >> 16));
  const float o0 = t0*cv - t1*sv, o1 = t0*sv + t1*cv;
  *p = (unsigned int)f2b(o0) | ((unsigned int)f2b(o1) << 16);
}

// ---------------- GEMM: C[M,N] = A[M,K] @ B[N,K]^T (bf16 in, f32 acc) ----------
// EPI: 1 = bf16 store, 2 = f32 residual add in-place (outf += acc),
//      3 = bf16 store of silu(gate)*acc
template<int EPI>
__global__ __launch_bounds__(256, 2)
void gemm_bt(const bhalf* __restrict__ A, const bhalf* __restrict__ B,
             const int N, const int K,
             const bhalf* __restrict__ gate,
             float* __restrict__ outf, bhalf* __restrict__ outb) {
  __shared__ bhalf As[128*32];
  __shared__ bhalf Bs[128*32];
  const int tid = threadIdx.x;
  const int w = tid >> 6, l = tid & 63;
  const int l15 = l & 15, lg = l >> 4;
  const int ntn = N >> 7;
  // bijective XCD swizzle (m204)
  const int nblocks = gridDim.x;
  const int qq = nblocks >> 3, rr = nblocks & 7;
  const int xcd = blockIdx.x & 7, loc = blockIdx.x >> 3;
  const int swz = (xcd < rr) ? (xcd*(qq+1) + loc) : (rr*(qq+1) + (xcd-rr)*qq + loc);
  const size_t m0 = (size_t)(swz / ntn) << 7;
  const size_t n0 = (size_t)(swz % ntn) << 7;
  f32x4 acc[4][4] = {};
  const int wr = w >> 1, wc = w & 1;
  const int stgrow = l >> 2;            // 16 rows per 1KB chunk
  const int stgcol = (l & 3) << 3;      // 8 bf16 per lane
  const int nk = K >> 5;
  for (int kt = 0; kt < nk; ++kt) {
    const int k0 = kt << 5;
    #pragma unroll
    for (int it = 0; it < 2; ++it) {
      const int c = it*4 + w;           // chunk 0..7, wave-uniform LDS base
      const int row = c*16 + stgrow;
      gload16(&A[(m0 + row)*K + k0 + stgcol], &As[c*512]);
      gload16(&B[(n0 + row)*K + k0 + stgcol], &Bs[c*512]);
    }
    __syncthreads();                    // drains vmcnt -> staging visible
    bf16x8 af[4], bfr[4];
    #pragma unroll
    for (int m = 0; m < 4; ++m)
      af[m] = *(const bf16x8*)&As[(wr*64 + m*16 + l15)*32 + lg*8];
    #pragma unroll
    for (int n = 0; n < 4; ++n)
      bfr[n] = *(const bf16x8*)&Bs[(wc*64 + n*16 + l15)*32 + lg*8];
    #pragma unroll
    for (int m = 0; m < 4; ++m)
      #pragma unroll
      for (int n = 0; n < 4; ++n)
        acc[m][n] = mfma16(af[m], bfr[n], acc[m][n]);
    __syncthreads();                    // all waves done reading before overwrite
  }
  #pragma unroll
  for (int m = 0; m < 4; ++m) {
    const size_t row = m0 + wr*64 + m*16 + lg*4;
    #pragma unroll
    for (int n = 0; n < 4; ++n) {
      const size_t col = n0 + wc*64 + n*16 + l15;
      #pragma unroll
      for (int r2 = 0; r2 < 4; ++r2) {
        const size_t idx = (row + r2)*(size_t)N + col;
        const float v = acc[m][n][r2];
        if constexpr (EPI == 1) {
          outb[idx] = f2b(v);
        } else if constexpr (EPI == 2) {
          outf[idx] += v;
        } else {
          const float g = b2f(gate[idx]);
          const float si = g / (1.0f + __expf(-g));
          outb[idx] = f2b(si * v);
        }
      }
    }
  }
}

// ---------------- Flash attention (causal, GQA 4:1, P cast to bf16) ------------
__global__ __launch_bounds__(256, 2)
void attn_k(const bhalf* __restrict__ qb, const bhalf* __restrict__ kb,
            const bhalf* __restrict__ vb, bhalf* __restrict__ ob) {
  __shared__ bhalf Ks[64][144];    // K tile, padded (4-way bank conflict max)
  __shared__ bhalf Vt[128][80];    // V tile transposed [d][key], padded
  __shared__ bhalf Ps[4][16][80];  // per-wave P tile
  const int h  = blockIdx.x >> 5;
  const int qt = blockIdx.x & 31;
  const int kvh = h >> 2;
  const int tid = threadIdx.x;
  const int w = tid >> 6, l = tid & 63;
  const int l15 = l & 15, lg = l >> 4;
  const int q0 = qt << 6;

  bf16x8 qf[4];  // wave's 16 q-rows held in registers
  {
    const bhalf* qrow = qb + (size_t)(q0 + w*16 + l15)*DM + h*HD + lg*8;
    #pragma unroll
    for (int kc = 0; kc < 4; ++kc) qf[kc] = *(const bf16x8*)(qrow + kc*32);
  }
  float m_r[4] = {-3e38f,-3e38f,-3e38f,-3e38f};
  float l_r[4] = {0.f,0.f,0.f,0.f};
  f32x4 acc_o[8] = {};
  const float scale = 0.08838834764831845f;
  const int nt = qt + 1;
  for (int t = 0; t < nt; ++t) {
    const int k0 = t << 6;
    __syncthreads();  // prior tile's LDS reads complete before overwrite
    #pragma unroll
    for (int it = 0; it < 4; ++it) {               // K tile 64x128
      const int e = it*256 + tid;
      const int row = e >> 4;
      const int col = (e & 15) << 3;
      *(int4*)&Ks[row][col] =
          *(const int4*)(kb + (size_t)(k0 + row)*KVD + kvh*HD + col);
    }
    {                                              // V tile transposed
      const int d = tid & 127, g = tid >> 7;
      const bhalf* vp = vb + (size_t)(k0 + g*32)*KVD + kvh*HD + d;
      #pragma unroll
      for (int kk8 = 0; kk8 < 4; ++kk8) {
        int4 o; bhalf* tt = (bhalf*)&o;
        #pragma unroll
        for (int j2 = 0; j2 < 8; ++j2) tt[j2] = vp[(size_t)(kk8*8 + j2)*KVD];
        *(int4*)&Vt[d][g*32 + kk8*8] = o;
      }
    }
    __syncthreads();
    f32x4 sa[4] = {};
    #pragma unroll
    for (int kc = 0; kc < 4; ++kc)
      #pragma unroll
      for (int n = 0; n < 4; ++n) {
        bf16x8 kf = *(const bf16x8*)&Ks[n*16 + l15][kc*32 + lg*8];
        sa[n] = mfma16(qf[kc], kf, sa[n]);
      }
    const bool masked = (t == qt);
    #pragma unroll
    for (int r = 0; r < 4; ++r) {
      const int qg = q0 + w*16 + lg*4 + r;
      float sv[4];
      #pragma unroll
      for (int n = 0; n < 4; ++n) {
        float s = sa[n][r] * scale;
        if (masked && (k0 + n*16 + l15 > qg)) s = -3e38f;
        sv[n] = s;
      }
      float tm = fmaxf(fmaxf(sv[0], sv[1]), fmaxf(sv[2], sv[3]));
      tm = fmaxf(tm, __shfl_xor(tm, 1));
      tm = fmaxf(tm, __shfl_xor(tm, 2));
      tm = fmaxf(tm, __shfl_xor(tm, 4));
      tm = fmaxf(tm, __shfl_xor(tm, 8));
      const float mn = fmaxf(m_r[r], tm);
      const float alpha = __expf(m_r[r] - mn);
      float pv[4], psum = 0.f;
      #pragma unroll
      for (int n = 0; n < 4; ++n) { pv[n] = __expf(sv[n] - mn); psum += pv[n]; }
      psum += __shfl_xor(psum, 1);
      psum += __shfl_xor(psum, 2);
      psum += __shfl_xor(psum, 4);
      psum += __shfl_xor(psum, 8);
      l_r[r] = l_r[r]*alpha + psum;
      m_r[r] = mn;
      #pragma unroll
      for (int n2 = 0; n2 < 8; ++n2) acc_o[n2][r] *= alpha;
      #pragma unroll
      for (int n = 0; n < 4; ++n) Ps[w][lg*4 + r][n*16 + l15] = f2b(pv[n]);
    }
    #pragma unroll
    for (int kk = 0; kk < 2; ++kk) {
      bf16x8 pa = *(const bf16x8*)&Ps[w][l15][kk*32 + lg*8];
      #pragma unroll
      for (int n2 = 0; n2 < 8; ++n2) {
        bf16x8 vf = *(const bf16x8*)&Vt[n2*16 + l15][kk*32 + lg*8];
        acc_o[n2] = mfma16(pa, vf, acc_o[n2]);
      }
    }
  }
  #pragma unroll
  for (int r = 0; r < 4; ++r) {
    const float inv = 1.0f / l_r[r];
    bhalf* orow = ob + (size_t)(q0 + w*16 + lg*4 + r)*DM + h*HD;
    #pragma unroll
    for (int n2 = 0; n2 < 8; ++n2) orow[n2*16 + l15] = f2b(acc_o[n2][r] * inv);
  }
}

// ---------------- host ----------------
extern "C" void kernel_launch(void* const* d_in, const int* in_sizes, int n_in,
                              void* d_out, int out_size, void* d_ws, size_t ws_size,
                              hipStream_t stream) {
  (void)in_sizes; (void)n_in; (void)out_size; (void)ws_size;
  const float* x_in = (const float*)d_in[0];
  const float* fcos = (const float*)d_in[1];
  const float* fsin = (const float*)d_in[2];
  const float* anw  = (const float*)d_in[3];
  const float* wq   = (const float*)d_in[4];
  const float* wk   = (const float*)d_in[5];
  const float* wv   = (const float*)d_in[6];
  const float* wo   = (const float*)d_in[7];
  const float* fnw  = (const float*)d_in[8];
  const float* w1   = (const float*)d_in[9];
  const float* w2   = (const float*)d_in[10];
  const float* w3   = (const float*)d_in[11];
  float* x = (float*)d_out;

  char* p = (char*)d_ws;
  auto carve = [&](size_t elems) {
    bhalf* r = (bhalf*)p; p += ((elems*2 + 255) & ~(size_t)255); return r;
  };
  bhalf* wq_b = carve((size_t)NLAYER*DM*DM);
  bhalf* wk_b = carve((size_t)NLAYER*KVD*DM);
  bhalf* wv_b = carve((size_t)NLAYER*KVD*DM);
  bhalf* wo_b = carve((size_t)NLAYER*DM*DM);
  bhalf* w1_b = carve((size_t)NLAYER*FF*DM);
  bhalf* w2_b = carve((size_t)NLAYER*DM*FF);
  bhalf* w3_b = carve((size_t)NLAYER*FF*DM);
  bhalf* hn   = carve((size_t)SLEN*DM);
  bhalf* qb   = carve((size_t)SLEN*DM);
  bhalf* kb   = carve((size_t)SLEN*KVD);
  bhalf* vb   = carve((size_t)SLEN*KVD);
  bhalf* ab   = carve((size_t)SLEN*DM);
  bhalf* g1   = carve((size_t)SLEN*FF);

  hipMemcpyAsync(x, x_in, (size_t)SLEN*DM*sizeof(float),
                 hipMemcpyDeviceToDevice, stream);

  cvt_f32_bf16<<<2048,256,0,stream>>>(wq, wq_b, (size_t)NLAYER*DM*DM);
  cvt_f32_bf16<<<2048,256,0,stream>>>(wk, wk_b, (size_t)NLAYER*KVD*DM);
  cvt_f32_bf16<<<2048,256,0,stream>>>(wv, wv_b, (size_t)NLAYER*KVD*DM);
  cvt_f32_bf16<<<2048,256,0,stream>>>(wo, wo_b, (size_t)NLAYER*DM*DM);
  cvt_f32_bf16<<<2048,256,0,stream>>>(w1, w1_b, (size_t)NLAYER*FF*DM);
  cvt_f32_bf16<<<2048,256,0,stream>>>(w2, w2_b, (size_t)NLAYER*DM*FF);
  cvt_f32_bf16<<<2048,256,0,stream>>>(w3, w3_b, (size_t)NLAYER*FF*DM);

  for (int l = 0; l < NLAYER; ++l) {
    rmsnorm_k<<<SLEN,256,0,stream>>>(x, anw + l*DM, hn);
    gemm_bt<1><<<256,256,0,stream>>>(hn, wq_b + (size_t)l*DM*DM,  DM,  DM, nullptr, nullptr, qb);
    gemm_bt<1><<<64, 256,0,stream>>>(hn, wk_b + (size_t)l*KVD*DM, KVD, DM, nullptr, nullptr, kb);
    gemm_bt<1><<<64, 256,0,stream>>>(hn, wv_b + (size_t)l*KVD*DM, KVD, DM, nullptr, nullptr, vb);
    rope_k<<<SLEN*NH*64/256,  256,0,stream>>>(qb, fcos, fsin, NH);
    rope_k<<<SLEN*NKVH*64/256,256,0,stream>>>(kb, fcos, fsin, NKVH);
    attn_k<<<NH*(SLEN/64),256,0,stream>>>(qb, kb, vb, ab);
    gemm_bt<2><<<256,256,0,stream>>>(ab, wo_b + (size_t)l*DM*DM, DM, DM, nullptr, x, nullptr);
    rmsnorm_k<<<SLEN,256,0,stream>>>(x, fnw + l*DM, hn);
    gemm_bt<1><<<1024,256,0,stream>>>(hn, w1_b + (size_t)l*FF*DM, FF, DM, nullptr, nullptr, g1);
    gemm_bt<3><<<1024,256,0,stream>>>(hn, w3_b + (size_t)l*FF*DM, FF, DM, g1, nullptr, g1);
    gemm_bt<2><<<256, 256,0,stream>>>(g1, w2_b + (size_t)l*DM*FF, DM, FF, nullptr, x, nullptr);
  }
}

// Round 4
// 1734.946 us; speedup vs baseline: 1.0450x; 1.0450x over previous
//
#include <hip/hip_runtime.h>

#define SLEN 2048
#define DM   2048
#define NH   16
#define NKVH 4
#define HD   128
#define KVD  512
#define FF   8192
#define NLAYER 2
#define EPSV 1e-5f

typedef unsigned short bhalf;
typedef __attribute__((__ext_vector_type__(8))) __bf16 bf16x8;
typedef __attribute__((__ext_vector_type__(4))) float f32x4;

__device__ __forceinline__ float b2f(bhalf u) {
  union { unsigned int i; float f; } v; v.i = ((unsigned int)u) << 16; return v.f;
}
__device__ __forceinline__ bhalf f2b(float f) {
  unsigned int x = __float_as_uint(f);
  return (bhalf)((x + 0x7fffu + ((x >> 16) & 1u)) >> 16);  // RNE
}

typedef __attribute__((address_space(1))) const void gas_cvoid;
typedef __attribute__((address_space(3))) void las_void;
__device__ __forceinline__ void gload16(const void* g, void* l) {
  __builtin_amdgcn_global_load_lds((gas_cvoid*)g, (las_void*)l, 16, 0, 0);
}
__device__ __forceinline__ f32x4 mfma16(bf16x8 a, bf16x8 b, f32x4 c) {
  return __builtin_amdgcn_mfma_f32_16x16x32_bf16(a, b, c, 0, 0, 0);
}

// ---------------- f32 -> bf16 convert ----------------
__global__ __launch_bounds__(256)
void cvt_f32_bf16(const float* __restrict__ in, bhalf* __restrict__ out, size_t n) {
  size_t i = ((size_t)blockIdx.x * 256 + threadIdx.x) * 8;
  const size_t stride = (size_t)gridDim.x * 256 * 8;
  for (; i < n; i += stride) {
    float4 a = *(const float4*)(in + i);
    float4 b = *(const float4*)(in + i + 4);
    int4 o; bhalf* t = (bhalf*)&o;
    t[0]=f2b(a.x); t[1]=f2b(a.y); t[2]=f2b(a.z); t[3]=f2b(a.w);
    t[4]=f2b(b.x); t[5]=f2b(b.y); t[6]=f2b(b.z); t[7]=f2b(b.w);
    *(int4*)(out + i) = o;
  }
}

// ---------------- RMSNorm: f32 in -> bf16 out ----------------
__global__ __launch_bounds__(256)
void rmsnorm_k(const float* __restrict__ x, const float* __restrict__ w,
               bhalf* __restrict__ out) {
  const int row = blockIdx.x;
  const int tid = threadIdx.x;
  const float4* xr = (const float4*)(x + (size_t)row * DM);
  float4 a = xr[tid*2], b = xr[tid*2 + 1];
  float ss = a.x*a.x + a.y*a.y + a.z*a.z + a.w*a.w
           + b.x*b.x + b.y*b.y + b.z*b.z + b.w*b.w;
  #pragma unroll
  for (int off = 32; off > 0; off >>= 1) ss += __shfl_down(ss, off);
  __shared__ float red[5];
  const int wv = tid >> 6, l = tid & 63;
  if (l == 0) red[wv] = ss;
  __syncthreads();
  if (tid == 0) red[4] = rsqrtf((red[0]+red[1]+red[2]+red[3]) * (1.0f/DM) + EPSV);
  __syncthreads();
  const float rs = red[4];
  const float* wp = w + tid*8;
  float vals[8] = {a.x,a.y,a.z,a.w,b.x,b.y,b.z,b.w};
  int4 o; bhalf* t = (bhalf*)&o;
  #pragma unroll
  for (int j = 0; j < 8; ++j) t[j] = f2b(vals[j] * rs * wp[j]);
  *(int4*)(out + (size_t)row*DM + tid*8) = o;
}

// ---------------- RoPE (in-place on bf16, pairs along last dim) ----------------
__global__ __launch_bounds__(256)
void rope_k(bhalf* __restrict__ t, const float* __restrict__ c,
            const float* __restrict__ s, int nheads) {
  const int idx = blockIdx.x * 256 + threadIdx.x;  // s*nheads*64 exact
  const int j  = idx & 63;
  const int hh = (idx >> 6) % nheads;
  const int sp = idx / (nheads * 64);
  const float cv = c[sp*64 + j], sv = s[sp*64 + j];
  unsigned int* p = (unsigned int*)(t + ((size_t)sp*nheads + hh)*HD + 2*j);
  const unsigned int pv = *p;
  const float t0 = b2f((bhalf)(pv & 0xffffu)), t1 = b2f((bhalf)(pv >> 16));
  const float o0 = t0*cv - t1*sv, o1 = t0*sv + t1*cv;
  *p = (unsigned int)f2b(o0) | ((unsigned int)f2b(o1) << 16);
}

// ---------------- GEMM (m97-structure, 128x128): C = A @ B^T ----------
// EPI: 1 = bf16 store, 2 = f32 residual add in-place, 3 = silu(gate)*acc bf16
template<int EPI>
__global__ __launch_bounds__(256, 2)
void gemm_bt(const bhalf* __restrict__ A, const bhalf* __restrict__ B,
             const int N, const int K,
             const bhalf* __restrict__ gate,
             float* __restrict__ outf, bhalf* __restrict__ outb) {
  __shared__ bhalf As[128*32];
  __shared__ bhalf Bs[128*32];
  const int tid = threadIdx.x;
  const int w = tid >> 6, l = tid & 63;
  const int l15 = l & 15, lg = l >> 4;
  const int ntn = N >> 7;
  const int nblocks = gridDim.x;
  const int qq = nblocks >> 3, rr = nblocks & 7;
  const int xcd = blockIdx.x & 7, loc = blockIdx.x >> 3;
  const int swz = (xcd < rr) ? (xcd*(qq+1) + loc) : (rr*(qq+1) + (xcd-rr)*qq + loc);
  const size_t m0 = (size_t)(swz / ntn) << 7;
  const size_t n0 = (size_t)(swz % ntn) << 7;
  f32x4 acc[4][4] = {};
  const int wr = w >> 1, wc = w & 1;
  const int stgrow = l >> 2;
  const int stgcol = (l & 3) << 3;
  const int nk = K >> 5;
  for (int kt = 0; kt < nk; ++kt) {
    const int k0 = kt << 5;
    #pragma unroll
    for (int it = 0; it < 2; ++it) {
      const int c = it*4 + w;
      const int row = c*16 + stgrow;
      gload16(&A[(m0 + row)*K + k0 + stgcol], &As[c*512]);
      gload16(&B[(n0 + row)*K + k0 + stgcol], &Bs[c*512]);
    }
    __syncthreads();
    bf16x8 af[4], bfr[4];
    #pragma unroll
    for (int m = 0; m < 4; ++m)
      af[m] = *(const bf16x8*)&As[(wr*64 + m*16 + l15)*32 + lg*8];
    #pragma unroll
    for (int n = 0; n < 4; ++n)
      bfr[n] = *(const bf16x8*)&Bs[(wc*64 + n*16 + l15)*32 + lg*8];
    #pragma unroll
    for (int m = 0; m < 4; ++m)
      #pragma unroll
      for (int n = 0; n < 4; ++n)
        acc[m][n] = mfma16(af[m], bfr[n], acc[m][n]);
    __syncthreads();
  }
  #pragma unroll
  for (int m = 0; m < 4; ++m) {
    const size_t row = m0 + wr*64 + m*16 + lg*4;
    #pragma unroll
    for (int n = 0; n < 4; ++n) {
      const size_t col = n0 + wc*64 + n*16 + l15;
      #pragma unroll
      for (int r2 = 0; r2 < 4; ++r2) {
        const size_t idx = (row + r2)*(size_t)N + col;
        const float v = acc[m][n][r2];
        if constexpr (EPI == 1) {
          outb[idx] = f2b(v);
        } else if constexpr (EPI == 2) {
          outf[idx] += v;
        } else {
          const float g = b2f(gate[idx]);
          const float si = g / (1.0f + __expf(-g));
          outb[idx] = f2b(si * v);
        }
      }
    }
  }
}

// ------------- gemm256: 256x256 tile, BK=32, 3-buffer counted-vmcnt pipeline ----
// C[M,N] = A[M,Ktot] @ B[N,Ktot]^T over K slice [k0, k0+klen).
// Requires: M%256==0, N%256==0, klen%32==0, klen/32 >= 3.
// grid = dim3((M/256)*(N/256), splits); k0 = blockIdx.y*klen.
// EPI: 1 bf16 store; 2 f32 +=; 3 silu(gate)*acc bf16; 5 f32 atomicAdd (split-K).
template<int EPI>
__global__ __launch_bounds__(512, 2)
void gemm256(const bhalf* __restrict__ A, const bhalf* __restrict__ B,
             const int N, const int lda, const int klen,
             const bhalf* __restrict__ gate, float* __restrict__ outf,
             bhalf* __restrict__ outb) {
  __shared__ __align__(16) bhalf As[3][256*32];   // 3 x 16 KiB
  __shared__ __align__(16) bhalf Bs[3][256*32];   // 3 x 16 KiB
  const int tid = threadIdx.x;
  const int w = tid >> 6, l = tid & 63;
  const int l15 = l & 15, lg = l >> 4;
  const int rdswz = (l15 >> 1) & 3;          // T2 swizzle for reads
  const int wr = w >> 2, wc = w & 3;         // 2x4 wave grid, per-wave 128x64
  const int ntn = N >> 8;
  const int nblocks = gridDim.x;             // bijective XCD swizzle (m204)
  const int qq = nblocks >> 3, rr = nblocks & 7;
  const int xcd = blockIdx.x & 7, loc = blockIdx.x >> 3;
  const int sb = (xcd < rr) ? (xcd*(qq+1) + loc) : (rr*(qq+1) + (xcd-rr)*qq + loc);
  const size_t m0 = (size_t)(sb / ntn) << 8;
  const size_t n0 = (size_t)(sb % ntn) << 8;
  const int k0 = blockIdx.y * klen;
  const int nk = klen >> 5;
  // staging: LDS linear dest, inverse-swizzled global source (rule 21)
  const int srow = l >> 2;
  const int scol = ((l & 3) ^ ((l >> 3) & 3)) << 3;
  const bhalf* Ag = A + m0 * (size_t)lda + k0;
  const bhalf* Bg = B + n0 * (size_t)lda + k0;

  auto stage = [&](int kt, int buf) {
    #pragma unroll
    for (int r = 0; r < 2; ++r) {
      const int chunk = r*8 + w;                       // wave-uniform
      const size_t go = (size_t)(chunk*16 + srow)*lda + kt*32 + scol;
      gload16(Ag + go, &As[buf][chunk*512]);
      gload16(Bg + go, &Bs[buf][chunk*512]);
    }
  };

  f32x4 acc[8][4] = {};
  auto compute = [&](int cb) {
    const bhalf* Ab = As[cb];
    const bhalf* Bb = Bs[cb];
    const int co = (lg ^ rdswz) << 3;
    bf16x8 bfr[4], am[4];
    #pragma unroll
    for (int n = 0; n < 4; ++n)
      bfr[n] = *(const bf16x8*)&Bb[(wc*64 + n*16 + l15)*32 + co];
    #pragma unroll
    for (int m = 0; m < 4; ++m)
      am[m] = *(const bf16x8*)&Ab[(wr*128 + m*16 + l15)*32 + co];
    __builtin_amdgcn_s_setprio(1);
    #pragma unroll
    for (int m = 0; m < 4; ++m)
      #pragma unroll
      for (int n = 0; n < 4; ++n)
        acc[m][n] = mfma16(am[m], bfr[n], acc[m][n]);
    __builtin_amdgcn_s_setprio(0);
    #pragma unroll
    for (int m = 0; m < 4; ++m)
      am[m] = *(const bf16x8*)&Ab[(wr*128 + 64 + m*16 + l15)*32 + co];
    __builtin_amdgcn_s_setprio(1);
    #pragma unroll
    for (int m = 0; m < 4; ++m)
      #pragma unroll
      for (int n = 0; n < 4; ++n)
        acc[m + 4][n] = mfma16(am[m], bfr[n], acc[m + 4][n]);
    __builtin_amdgcn_s_setprio(0);
  };

  // prologue: stage tiles 0,1; wait tile 0 landed (tile 1's 4 may fly)
  stage(0, 0);
  stage(1, 1);
  asm volatile("s_waitcnt vmcnt(4)" ::: "memory");
  __builtin_amdgcn_s_barrier();
  asm volatile("" ::: "memory");

  int cb = 0, pb = 2;
  for (int kt = 0; kt < nk - 2; ++kt) {
    stage(kt + 2, pb);                      // buf (kt+2)%3: untouched by readers
    compute(cb);
    asm volatile("s_waitcnt vmcnt(4)" ::: "memory");   // tile kt+1 landed
    __builtin_amdgcn_s_barrier();
    asm volatile("" ::: "memory");
    cb = (cb + 1 == 3) ? 0 : cb + 1;
    pb = (pb + 1 == 3) ? 0 : pb + 1;
  }
  compute(cb);                              // tile nk-2
  asm volatile("s_waitcnt vmcnt(0)" ::: "memory");     // drain: tile nk-1 landed
  __builtin_amdgcn_s_barrier();
  asm volatile("" ::: "memory");
  cb = (cb + 1 == 3) ? 0 : cb + 1;
  compute(cb);                              // tile nk-1

  #pragma unroll
  for (int m = 0; m < 8; ++m) {
    const size_t row = m0 + wr*128 + m*16 + lg*4;
    #pragma unroll
    for (int n = 0; n < 4; ++n) {
      const size_t col = n0 + wc*64 + n*16 + l15;
      #pragma unroll
      for (int r2 = 0; r2 < 4; ++r2) {
        const size_t idx = (row + r2) * (size_t)N + col;
        const float v = acc[m][n][r2];
        if constexpr (EPI == 1) {
          outb[idx] = f2b(v);
        } else if constexpr (EPI == 2) {
          outf[idx] += v;
        } else if constexpr (EPI == 3) {
          const float g = b2f(gate[idx]);
          outb[idx] = f2b((g / (1.0f + __expf(-g))) * v);
        } else {
          atomicAdd(&outf[idx], v);         // split-K accumulate
        }
      }
    }
  }
}

// ---------------- Flash attention (causal, GQA 4:1, P cast to bf16) ------------
__global__ __launch_bounds__(256, 2)
void attn_k(const bhalf* __restrict__ qb, const bhalf* __restrict__ kb,
            const bhalf* __restrict__ vb, bhalf* __restrict__ ob) {
  __shared__ bhalf Ks[64][144];
  __shared__ bhalf Vt[128][80];
  __shared__ bhalf Ps[4][16][80];
  const int h  = blockIdx.x >> 5;
  const int qt = blockIdx.x & 31;
  const int kvh = h >> 2;
  const int tid = threadIdx.x;
  const int w = tid >> 6, l = tid & 63;
  const int l15 = l & 15, lg = l >> 4;
  const int q0 = qt << 6;

  bf16x8 qf[4];
  {
    const bhalf* qrow = qb + (size_t)(q0 + w*16 + l15)*DM + h*HD + lg*8;
    #pragma unroll
    for (int kc = 0; kc < 4; ++kc) qf[kc] = *(const bf16x8*)(qrow + kc*32);
  }
  float m_r[4] = {-3e38f,-3e38f,-3e38f,-3e38f};
  float l_r[4] = {0.f,0.f,0.f,0.f};
  f32x4 acc_o[8] = {};
  const float scale = 0.08838834764831845f;
  const int nt = qt + 1;
  for (int t = 0; t < nt; ++t) {
    const int k0 = t << 6;
    __syncthreads();
    #pragma unroll
    for (int it = 0; it < 4; ++it) {
      const int e = it*256 + tid;
      const int row = e >> 4;
      const int col = (e & 15) << 3;
      *(int4*)&Ks[row][col] =
          *(const int4*)(kb + (size_t)(k0 + row)*KVD + kvh*HD + col);
    }
    {
      const int d = tid & 127, g = tid >> 7;
      const bhalf* vp = vb + (size_t)(k0 + g*32)*KVD + kvh*HD + d;
      #pragma unroll
      for (int kk8 = 0; kk8 < 4; ++kk8) {
        int4 o; bhalf* tt = (bhalf*)&o;
        #pragma unroll
        for (int j2 = 0; j2 < 8; ++j2) tt[j2] = vp[(size_t)(kk8*8 + j2)*KVD];
        *(int4*)&Vt[d][g*32 + kk8*8] = o;
      }
    }
    __syncthreads();
    f32x4 sa[4] = {};
    #pragma unroll
    for (int kc = 0; kc < 4; ++kc)
      #pragma unroll
      for (int n = 0; n < 4; ++n) {
        bf16x8 kf = *(const bf16x8*)&Ks[n*16 + l15][kc*32 + lg*8];
        sa[n] = mfma16(qf[kc], kf, sa[n]);
      }
    const bool masked = (t == qt);
    #pragma unroll
    for (int r = 0; r < 4; ++r) {
      const int qg = q0 + w*16 + lg*4 + r;
      float sv[4];
      #pragma unroll
      for (int n = 0; n < 4; ++n) {
        float s = sa[n][r] * scale;
        if (masked && (k0 + n*16 + l15 > qg)) s = -3e38f;
        sv[n] = s;
      }
      float tm = fmaxf(fmaxf(sv[0], sv[1]), fmaxf(sv[2], sv[3]));
      tm = fmaxf(tm, __shfl_xor(tm, 1));
      tm = fmaxf(tm, __shfl_xor(tm, 2));
      tm = fmaxf(tm, __shfl_xor(tm, 4));
      tm = fmaxf(tm, __shfl_xor(tm, 8));
      const float mn = fmaxf(m_r[r], tm);
      const float alpha = __expf(m_r[r] - mn);
      float pv[4], psum = 0.f;
      #pragma unroll
      for (int n = 0; n < 4; ++n) { pv[n] = __expf(sv[n] - mn); psum += pv[n]; }
      psum += __shfl_xor(psum, 1);
      psum += __shfl_xor(psum, 2);
      psum += __shfl_xor(psum, 4);
      psum += __shfl_xor(psum, 8);
      l_r[r] = l_r[r]*alpha + psum;
      m_r[r] = mn;
      #pragma unroll
      for (int n2 = 0; n2 < 8; ++n2) acc_o[n2][r] *= alpha;
      #pragma unroll
      for (int n = 0; n < 4; ++n) Ps[w][lg*4 + r][n*16 + l15] = f2b(pv[n]);
    }
    #pragma unroll
    for (int kk = 0; kk < 2; ++kk) {
      bf16x8 pa = *(const bf16x8*)&Ps[w][l15][kk*32 + lg*8];
      #pragma unroll
      for (int n2 = 0; n2 < 8; ++n2) {
        bf16x8 vf = *(const bf16x8*)&Vt[n2*16 + l15][kk*32 + lg*8];
        acc_o[n2] = mfma16(pa, vf, acc_o[n2]);
      }
    }
  }
  #pragma unroll
  for (int r = 0; r < 4; ++r) {
    const float inv = 1.0f / l_r[r];
    bhalf* orow = ob + (size_t)(q0 + w*16 + lg*4 + r)*DM + h*HD;
    #pragma unroll
    for (int n2 = 0; n2 < 8; ++n2) orow[n2*16 + l15] = f2b(acc_o[n2][r] * inv);
  }
}

// ---------------- host ----------------
extern "C" void kernel_launch(void* const* d_in, const int* in_sizes, int n_in,
                              void* d_out, int out_size, void* d_ws, size_t ws_size,
                              hipStream_t stream) {
  (void)in_sizes; (void)n_in; (void)out_size; (void)ws_size;
  const float* x_in = (const float*)d_in[0];
  const float* fcos = (const float*)d_in[1];
  const float* fsin = (const float*)d_in[2];
  const float* anw  = (const float*)d_in[3];
  const float* wq   = (const float*)d_in[4];
  const float* wk   = (const float*)d_in[5];
  const float* wv   = (const float*)d_in[6];
  const float* wo   = (const float*)d_in[7];
  const float* fnw  = (const float*)d_in[8];
  const float* w1   = (const float*)d_in[9];
  const float* w2   = (const float*)d_in[10];
  const float* w3   = (const float*)d_in[11];
  float* x = (float*)d_out;

  char* p = (char*)d_ws;
  auto carve = [&](size_t elems) {
    bhalf* r = (bhalf*)p; p += ((elems*2 + 255) & ~(size_t)255); return r;
  };
  bhalf* wq_b = carve((size_t)NLAYER*DM*DM);
  bhalf* wk_b = carve((size_t)NLAYER*KVD*DM);
  bhalf* wv_b = carve((size_t)NLAYER*KVD*DM);
  bhalf* wo_b = carve((size_t)NLAYER*DM*DM);
  bhalf* w1_b = carve((size_t)NLAYER*FF*DM);
  bhalf* w2_b = carve((size_t)NLAYER*DM*FF);
  bhalf* w3_b = carve((size_t)NLAYER*FF*DM);
  bhalf* hn   = carve((size_t)SLEN*DM);
  bhalf* qb   = carve((size_t)SLEN*DM);
  bhalf* kb   = carve((size_t)SLEN*KVD);
  bhalf* vb   = carve((size_t)SLEN*KVD);
  bhalf* ab   = carve((size_t)SLEN*DM);
  bhalf* g1   = carve((size_t)SLEN*FF);

  hipMemcpyAsync(x, x_in, (size_t)SLEN*DM*sizeof(float),
                 hipMemcpyDeviceToDevice, stream);

  cvt_f32_bf16<<<2048,256,0,stream>>>(wq, wq_b, (size_t)NLAYER*DM*DM);
  cvt_f32_bf16<<<2048,256,0,stream>>>(wk, wk_b, (size_t)NLAYER*KVD*DM);
  cvt_f32_bf16<<<2048,256,0,stream>>>(wv, wv_b, (size_t)NLAYER*KVD*DM);
  cvt_f32_bf16<<<2048,256,0,stream>>>(wo, wo_b, (size_t)NLAYER*DM*DM);
  cvt_f32_bf16<<<2048,256,0,stream>>>(w1, w1_b, (size_t)NLAYER*FF*DM);
  cvt_f32_bf16<<<2048,256,0,stream>>>(w2, w2_b, (size_t)NLAYER*DM*FF);
  cvt_f32_bf16<<<2048,256,0,stream>>>(w3, w3_b, (size_t)NLAYER*FF*DM);

  for (int l = 0; l < NLAYER; ++l) {
    rmsnorm_k<<<SLEN,256,0,stream>>>(x, anw + l*DM, hn);
    gemm_bt<1><<<256,256,0,stream>>>(hn, wq_b + (size_t)l*DM*DM,  DM,  DM, nullptr, nullptr, qb);
    gemm_bt<1><<<64, 256,0,stream>>>(hn, wk_b + (size_t)l*KVD*DM, KVD, DM, nullptr, nullptr, kb);
    gemm_bt<1><<<64, 256,0,stream>>>(hn, wv_b + (size_t)l*KVD*DM, KVD, DM, nullptr, nullptr, vb);
    rope_k<<<SLEN*NH*64/256,  256,0,stream>>>(qb, fcos, fsin, NH);
    rope_k<<<SLEN*NKVH*64/256,256,0,stream>>>(kb, fcos, fsin, NKVH);
    attn_k<<<NH*(SLEN/64),256,0,stream>>>(qb, kb, vb, ab);
    gemm_bt<2><<<256,256,0,stream>>>(ab, wo_b + (size_t)l*DM*DM, DM, DM, nullptr, x, nullptr);
    rmsnorm_k<<<SLEN,256,0,stream>>>(x, fnw + l*DM, hn);
    // FFN on the 256x256 counted-vmcnt pipeline
    gemm256<1><<<dim3((SLEN/256)*(FF/256),1),512,0,stream>>>(
        hn, w1_b + (size_t)l*FF*DM, FF, DM, DM, nullptr, nullptr, g1);
    gemm256<3><<<dim3((SLEN/256)*(FF/256),1),512,0,stream>>>(
        hn, w3_b + (size_t)l*FF*DM, FF, DM, DM, g1, nullptr, g1);
    gemm256<5><<<dim3((SLEN/256)*(DM/256),4),512,0,stream>>>(
        g1, w2_b + (size_t)l*DM*FF, DM, FF, FF/4, nullptr, x, nullptr);
  }
}

// Round 6
// 1550.176 us; speedup vs baseline: 1.1696x; 1.1192x over previous
//
#include <hip/hip_runtime.h>

#define SLEN 2048
#define DM   2048
#define NH   16
#define NKVH 4
#define HD   128
#define KVD  512
#define FF   8192
#define NLAYER 2
#define EPSV 1e-5f
#define QKVW 3072
#define KOFF 2048
#define VOFF 2560

typedef unsigned short bhalf;
typedef __attribute__((__ext_vector_type__(8))) __bf16 bf16x8;
typedef __attribute__((__ext_vector_type__(4))) float f32x4;

__device__ __forceinline__ float b2f(bhalf u) {
  union { unsigned int i; float f; } v; v.i = ((unsigned int)u) << 16; return v.f;
}
__device__ __forceinline__ bhalf f2b(float f) {
  unsigned int x = __float_as_uint(f);
  return (bhalf)((x + 0x7fffu + ((x >> 16) & 1u)) >> 16);  // RNE
}

typedef __attribute__((address_space(1))) const void gas_cvoid;
typedef __attribute__((address_space(3))) void las_void;
__device__ __forceinline__ void gload16(const void* g, void* l) {
  __builtin_amdgcn_global_load_lds((gas_cvoid*)g, (las_void*)l, 16, 0, 0);
}
__device__ __forceinline__ f32x4 mfma16(bf16x8 a, bf16x8 b, f32x4 c) {
  return __builtin_amdgcn_mfma_f32_16x16x32_bf16(a, b, c, 0, 0, 0);
}
__device__ __forceinline__ void barrier_raw() {
  asm volatile("" ::: "memory");
  __builtin_amdgcn_s_barrier();
  asm volatile("" ::: "memory");
}

// ---------------- f32 -> bf16 convert ----------------
__global__ __launch_bounds__(256)
void cvt_f32_bf16(const float* __restrict__ in, bhalf* __restrict__ out, size_t n) {
  size_t i = ((size_t)blockIdx.x * 256 + threadIdx.x) * 8;
  const size_t stride = (size_t)gridDim.x * 256 * 8;
  for (; i < n; i += stride) {
    float4 a = *(const float4*)(in + i);
    float4 b = *(const float4*)(in + i + 4);
    int4 o; bhalf* t = (bhalf*)&o;
    t[0]=f2b(a.x); t[1]=f2b(a.y); t[2]=f2b(a.z); t[3]=f2b(a.w);
    t[4]=f2b(b.x); t[5]=f2b(b.y); t[6]=f2b(b.z); t[7]=f2b(b.w);
    *(int4*)(out + i) = o;
  }
}

// ---------------- RMSNorm: f32 in -> bf16 out ----------------
__global__ __launch_bounds__(256)
void rmsnorm_k(const float* __restrict__ x, const float* __restrict__ w,
               bhalf* __restrict__ out) {
  const int row = blockIdx.x;
  const int tid = threadIdx.x;
  const float4* xr = (const float4*)(x + (size_t)row * DM);
  float4 a = xr[tid*2], b = xr[tid*2 + 1];
  float ss = a.x*a.x + a.y*a.y + a.z*a.z + a.w*a.w
           + b.x*b.x + b.y*b.y + b.z*b.z + b.w*b.w;
  #pragma unroll
  for (int off = 32; off > 0; off >>= 1) ss += __shfl_down(ss, off);
  __shared__ float red[5];
  const int wv = tid >> 6, l = tid & 63;
  if (l == 0) red[wv] = ss;
  __syncthreads();
  if (tid == 0) red[4] = rsqrtf((red[0]+red[1]+red[2]+red[3]) * (1.0f/DM) + EPSV);
  __syncthreads();
  const float rs = red[4];
  const float* wp = w + tid*8;
  float vals[8] = {a.x,a.y,a.z,a.w,b.x,b.y,b.z,b.w};
  int4 o; bhalf* t = (bhalf*)&o;
  #pragma unroll
  for (int j = 0; j < 8; ++j) t[j] = f2b(vals[j] * rs * wp[j]);
  *(int4*)(out + (size_t)row*DM + tid*8) = o;
}

// ---------------- RoPE (in-place on bf16, strided rows) ----------------
__global__ __launch_bounds__(256)
void rope_k(bhalf* __restrict__ t, const float* __restrict__ c,
            const float* __restrict__ s, int nheads, int rowstride, int off) {
  const int idx = blockIdx.x * 256 + threadIdx.x;  // s*nheads*64 exact
  const int j  = idx & 63;
  const int hh = (idx >> 6) % nheads;
  const int sp = idx / (nheads * 64);
  const float cv = c[sp*64 + j], sv = s[sp*64 + j];
  unsigned int* p = (unsigned int*)(t + (size_t)sp*rowstride + off + hh*HD + 2*j);
  const unsigned int pv = *p;
  const float t0 = b2f((bhalf)(pv & 0xffffu)), t1 = b2f((bhalf)(pv >> 16));
  const float o0 = t0*cv - t1*sv, o1 = t0*sv + t1*cv;
  *p = (unsigned int)f2b(o0) | ((unsigned int)f2b(o1) << 16);
}

// ---------------- GEMM (m97-structure, 128x128): C = A @ B^T ----------
// EPI: 1 = bf16 store, 2 = f32 residual add in-place, 3 = silu(gate)*acc bf16
template<int EPI>
__global__ __launch_bounds__(256, 2)
void gemm_bt(const bhalf* __restrict__ A, const bhalf* __restrict__ B,
             const int N, const int K,
             const bhalf* __restrict__ gate,
             float* __restrict__ outf, bhalf* __restrict__ outb) {
  __shared__ bhalf As[128*32];
  __shared__ bhalf Bs[128*32];
  const int tid = threadIdx.x;
  const int w = tid >> 6, l = tid & 63;
  const int l15 = l & 15, lg = l >> 4;
  const int ntn = N >> 7;
  const int nblocks = gridDim.x;
  const int qq = nblocks >> 3, rr = nblocks & 7;
  const int xcd = blockIdx.x & 7, loc = blockIdx.x >> 3;
  const int swz = (xcd < rr) ? (xcd*(qq+1) + loc) : (rr*(qq+1) + (xcd-rr)*qq + loc);
  const size_t m0 = (size_t)(swz / ntn) << 7;
  const size_t n0 = (size_t)(swz % ntn) << 7;
  f32x4 acc[4][4] = {};
  const int wr = w >> 1, wc = w & 1;
  const int stgrow = l >> 2;
  const int stgcol = (l & 3) << 3;
  const int nk = K >> 5;
  for (int kt = 0; kt < nk; ++kt) {
    const int k0 = kt << 5;
    #pragma unroll
    for (int it = 0; it < 2; ++it) {
      const int c = it*4 + w;
      const int row = c*16 + stgrow;
      gload16(&A[(m0 + row)*K + k0 + stgcol], &As[c*512]);
      gload16(&B[(n0 + row)*K + k0 + stgcol], &Bs[c*512]);
    }
    __syncthreads();
    bf16x8 af[4], bfr[4];
    #pragma unroll
    for (int m = 0; m < 4; ++m)
      af[m] = *(const bf16x8*)&As[(wr*64 + m*16 + l15)*32 + lg*8];
    #pragma unroll
    for (int n = 0; n < 4; ++n)
      bfr[n] = *(const bf16x8*)&Bs[(wc*64 + n*16 + l15)*32 + lg*8];
    #pragma unroll
    for (int m = 0; m < 4; ++m)
      #pragma unroll
      for (int n = 0; n < 4; ++n)
        acc[m][n] = mfma16(af[m], bfr[n], acc[m][n]);
    __syncthreads();
  }
  #pragma unroll
  for (int m = 0; m < 4; ++m) {
    const size_t row = m0 + wr*64 + m*16 + lg*4;
    #pragma unroll
    for (int n = 0; n < 4; ++n) {
      const size_t col = n0 + wc*64 + n*16 + l15;
      #pragma unroll
      for (int r2 = 0; r2 < 4; ++r2) {
        const size_t idx = (row + r2)*(size_t)N + col;
        const float v = acc[m][n][r2];
        if constexpr (EPI == 1) {
          outb[idx] = f2b(v);
        } else if constexpr (EPI == 2) {
          outf[idx] += v;
        } else {
          const float g = b2f(gate[idx]);
          const float si = g / (1.0f + __expf(-g));
          outb[idx] = f2b(si * v);
        }
      }
    }
  }
}

// ------------- gemm256: 256x256 tile, BK=32, 3-buffer counted-vmcnt pipeline,
//               2 phases per K-tile (16-MFMA clusters, T2+T3+T4+T5) -----------
// EPI: 1 bf16 store; 2 f32 +=; 3 silu(gate)*acc bf16; 5 f32 atomicAdd (split-K).
template<int EPI>
__global__ __launch_bounds__(512, 2)
void gemm256(const bhalf* __restrict__ A, const bhalf* __restrict__ B,
             const int N, const int lda, const int klen,
             const bhalf* __restrict__ gate, float* __restrict__ outf,
             bhalf* __restrict__ outb) {
  __shared__ __align__(16) bhalf As[3][256*32];   // 3 x 16 KiB
  __shared__ __align__(16) bhalf Bs[3][256*32];
  const int tid = threadIdx.x;
  const int w = tid >> 6, l = tid & 63;
  const int l15 = l & 15, lg = l >> 4;
  const int rdswz = (l15 >> 1) & 3;          // T2 swizzle for reads
  const int wr = w >> 2, wc = w & 3;         // 2x4 wave grid, per-wave 128x64
  const int ntn = N >> 8;
  const int nblocks = gridDim.x;             // bijective XCD swizzle (m204)
  const int qq = nblocks >> 3, rr = nblocks & 7;
  const int xcd = blockIdx.x & 7, loc = blockIdx.x >> 3;
  const int sw = (xcd < rr) ? (xcd*(qq+1) + loc) : (rr*(qq+1) + (xcd-rr)*qq + loc);
  const size_t m0 = (size_t)(sw / ntn) << 8;
  const size_t n0 = (size_t)(sw % ntn) << 8;
  const int k0 = blockIdx.y * klen;
  const int nk = klen >> 5;
  // staging: LDS linear dest, inverse-swizzled global source (rule 21)
  const int srow = l >> 2;
  const int scol = ((l & 3) ^ ((l >> 3) & 3)) << 3;
  const bhalf* Ag = A + m0 * (size_t)lda + k0;
  const bhalf* Bg = B + n0 * (size_t)lda + k0;

  auto stageA = [&](int kt, int bf) {
    #pragma unroll
    for (int r = 0; r < 2; ++r) {
      const int chunk = r*8 + w;                       // wave-uniform LDS base
      const size_t go = (size_t)(chunk*16 + srow)*lda + kt*32 + scol;
      gload16(Ag + go, &As[bf][chunk*512]);
    }
  };
  auto stageB = [&](int kt, int bf) {
    #pragma unroll
    for (int r = 0; r < 2; ++r) {
      const int chunk = r*8 + w;
      const size_t go = (size_t)(chunk*16 + srow)*lda + kt*32 + scol;
      gload16(Bg + go, &Bs[bf][chunk*512]);
    }
  };

  f32x4 acc[8][4] = {};
  const int co = (lg ^ rdswz) << 3;

  // one K-tile = 2 phases of {ds_read subtile, stage-issue, barrier,
  //                           setprio(1) 16 MFMA setprio(0), barrier}
  auto ktile = [&](int cb, int sbf, int kt2, bool stg) {
    const bhalf* Ab = As[cb];
    const bhalf* Bb = Bs[cb];
    bf16x8 bfr[4], am[4];
    // ---- phase 0: m-half 0 ----
    #pragma unroll
    for (int n = 0; n < 4; ++n)
      bfr[n] = *(const bf16x8*)&Bb[(wc*64 + n*16 + l15)*32 + co];
    #pragma unroll
    for (int m = 0; m < 4; ++m)
      am[m] = *(const bf16x8*)&Ab[(wr*128 + m*16 + l15)*32 + co];
    if (stg) stageA(kt2, sbf);
    barrier_raw();
    __builtin_amdgcn_s_setprio(1);
    #pragma unroll
    for (int m = 0; m < 4; ++m)
      #pragma unroll
      for (int n = 0; n < 4; ++n)
        acc[m][n] = mfma16(am[m], bfr[n], acc[m][n]);
    __builtin_amdgcn_s_setprio(0);
    barrier_raw();
    // ---- phase 1: m-half 1 ----
    #pragma unroll
    for (int m = 0; m < 4; ++m)
      am[m] = *(const bf16x8*)&Ab[(wr*128 + 64 + m*16 + l15)*32 + co];
    if (stg) stageB(kt2, sbf);
    barrier_raw();
    __builtin_amdgcn_s_setprio(1);
    #pragma unroll
    for (int m = 0; m < 4; ++m)
      #pragma unroll
      for (int n = 0; n < 4; ++n)
        acc[m + 4][n] = mfma16(am[m], bfr[n], acc[m + 4][n]);
    __builtin_amdgcn_s_setprio(0);
  };

  // prologue: stage tiles 0,1; wait tile 0 landed (tile 1's 4 may fly)
  stageA(0, 0); stageB(0, 0);
  stageA(1, 1); stageB(1, 1);
  asm volatile("s_waitcnt vmcnt(4)" ::: "memory");
  barrier_raw();

  int cb = 0;
  for (int kt = 0; kt < nk - 2; ++kt) {
    const int sbf = (cb + 2 >= 3) ? cb - 1 : cb + 2;   // (kt+2)%3
    ktile(cb, sbf, kt + 2, true);
    asm volatile("s_waitcnt vmcnt(4)" ::: "memory");   // tile kt+1 landed
    barrier_raw();
    cb = (cb + 1 == 3) ? 0 : cb + 1;
  }
  ktile(cb, 0, 0, false);                   // tile nk-2
  asm volatile("s_waitcnt vmcnt(0)" ::: "memory");     // drain: nk-1 landed
  barrier_raw();
  cb = (cb + 1 == 3) ? 0 : cb + 1;
  ktile(cb, 0, 0, false);                   // tile nk-1

  #pragma unroll
  for (int m = 0; m < 8; ++m) {
    const size_t row = m0 + wr*128 + m*16 + lg*4;
    #pragma unroll
    for (int n = 0; n < 4; ++n) {
      const size_t col = n0 + wc*64 + n*16 + l15;
      #pragma unroll
      for (int r2 = 0; r2 < 4; ++r2) {
        const size_t idx = (row + r2) * (size_t)N + col;
        const float v = acc[m][n][r2];
        if constexpr (EPI == 1) {
          outb[idx] = f2b(v);
        } else if constexpr (EPI == 2) {
          outf[idx] += v;
        } else if constexpr (EPI == 3) {
          const float g = b2f(gate[idx]);
          outb[idx] = f2b((g / (1.0f + __expf(-g))) * v);
        } else {
          atomicAdd(&outf[idx], v);         // split-K accumulate
        }
      }
    }
  }
}

// ---------------- Flash attention (causal, GQA 4:1, P cast to bf16) ------------
// Q,K,V packed in one [SLEN][QKVW] buffer (cols: Q 0..2047, K 2048.., V 2560..)
__global__ __launch_bounds__(256, 2)
void attn_k(const bhalf* __restrict__ qkv, bhalf* __restrict__ ob) {
  __shared__ bhalf Ks[64][144];
  __shared__ bhalf Vt[128][80];
  __shared__ bhalf Ps[4][16][80];
  const int h  = blockIdx.x >> 5;
  const int qt = blockIdx.x & 31;
  const int kvh = h >> 2;
  const int tid = threadIdx.x;
  const int w = tid >> 6, l = tid & 63;
  const int l15 = l & 15, lg = l >> 4;
  const int q0 = qt << 6;

  bf16x8 qf[4];
  {
    const bhalf* qrow = qkv + (size_t)(q0 + w*16 + l15)*QKVW + h*HD + lg*8;
    #pragma unroll
    for (int kc = 0; kc < 4; ++kc) qf[kc] = *(const bf16x8*)(qrow + kc*32);
  }
  float m_r[4] = {-3e38f,-3e38f,-3e38f,-3e38f};
  float l_r[4] = {0.f,0.f,0.f,0.f};
  f32x4 acc_o[8] = {};
  const float scale = 0.08838834764831845f;
  const int nt = qt + 1;
  for (int t = 0; t < nt; ++t) {
    const int k0 = t << 6;
    __syncthreads();
    #pragma unroll
    for (int it = 0; it < 4; ++it) {               // K tile 64x128
      const int e = it*256 + tid;
      const int row = e >> 4;
      const int col = (e & 15) << 3;
      *(int4*)&Ks[row][col] =
          *(const int4*)(qkv + (size_t)(k0 + row)*QKVW + KOFF + kvh*HD + col);
    }
    {                                              // V tile transposed
      const int d = tid & 127, g = tid >> 7;
      const bhalf* vp = qkv + (size_t)(k0 + g*32)*QKVW + VOFF + kvh*HD + d;
      #pragma unroll
      for (int kk8 = 0; kk8 < 4; ++kk8) {
        int4 o; bhalf* tt = (bhalf*)&o;
        #pragma unroll
        for (int j2 = 0; j2 < 8; ++j2) tt[j2] = vp[(size_t)(kk8*8 + j2)*QKVW];
        *(int4*)&Vt[d][g*32 + kk8*8] = o;
      }
    }
    __syncthreads();
    f32x4 sa[4] = {};
    #pragma unroll
    for (int kc = 0; kc < 4; ++kc)
      #pragma unroll
      for (int n = 0; n < 4; ++n) {
        bf16x8 kf = *(const bf16x8*)&Ks[n*16 + l15][kc*32 + lg*8];
        sa[n] = mfma16(qf[kc], kf, sa[n]);
      }
    const bool masked = (t == qt);
    #pragma unroll
    for (int r = 0; r < 4; ++r) {
      const int qg = q0 + w*16 + lg*4 + r;
      float sv[4];
      #pragma unroll
      for (int n = 0; n < 4; ++n) {
        float s = sa[n][r] * scale;
        if (masked && (k0 + n*16 + l15 > qg)) s = -3e38f;
        sv[n] = s;
      }
      float tm = fmaxf(fmaxf(sv[0], sv[1]), fmaxf(sv[2], sv[3]));
      tm = fmaxf(tm, __shfl_xor(tm, 1));
      tm = fmaxf(tm, __shfl_xor(tm, 2));
      tm = fmaxf(tm, __shfl_xor(tm, 4));
      tm = fmaxf(tm, __shfl_xor(tm, 8));
      const float mn = fmaxf(m_r[r], tm);
      const float alpha = __expf(m_r[r] - mn);
      float pv[4], psum = 0.f;
      #pragma unroll
      for (int n = 0; n < 4; ++n) { pv[n] = __expf(sv[n] - mn); psum += pv[n]; }
      psum += __shfl_xor(psum, 1);
      psum += __shfl_xor(psum, 2);
      psum += __shfl_xor(psum, 4);
      psum += __shfl_xor(psum, 8);
      l_r[r] = l_r[r]*alpha + psum;
      m_r[r] = mn;
      #pragma unroll
      for (int n2 = 0; n2 < 8; ++n2) acc_o[n2][r] *= alpha;
      #pragma unroll
      for (int n = 0; n < 4; ++n) Ps[w][lg*4 + r][n*16 + l15] = f2b(pv[n]);
    }
    #pragma unroll
    for (int kk = 0; kk < 2; ++kk) {
      bf16x8 pa = *(const bf16x8*)&Ps[w][l15][kk*32 + lg*8];
      #pragma unroll
      for (int n2 = 0; n2 < 8; ++n2) {
        bf16x8 vf = *(const bf16x8*)&Vt[n2*16 + l15][kk*32 + lg*8];
        acc_o[n2] = mfma16(pa, vf, acc_o[n2]);
      }
    }
  }
  #pragma unroll
  for (int r = 0; r < 4; ++r) {
    const float inv = 1.0f / l_r[r];
    bhalf* orow = ob + (size_t)(q0 + w*16 + lg*4 + r)*DM + h*HD;
    #pragma unroll
    for (int n2 = 0; n2 < 8; ++n2) orow[n2*16 + l15] = f2b(acc_o[n2][r] * inv);
  }
}

// ---------------- host ----------------
extern "C" void kernel_launch(void* const* d_in, const int* in_sizes, int n_in,
                              void* d_out, int out_size, void* d_ws, size_t ws_size,
                              hipStream_t stream) {
  (void)in_sizes; (void)n_in; (void)out_size; (void)ws_size;
  const float* x_in = (const float*)d_in[0];
  const float* fcos = (const float*)d_in[1];
  const float* fsin = (const float*)d_in[2];
  const float* anw  = (const float*)d_in[3];
  const float* wq   = (const float*)d_in[4];
  const float* wk   = (const float*)d_in[5];
  const float* wv   = (const float*)d_in[6];
  const float* wo   = (const float*)d_in[7];
  const float* fnw  = (const float*)d_in[8];
  const float* w1   = (const float*)d_in[9];
  const float* w2   = (const float*)d_in[10];
  const float* w3   = (const float*)d_in[11];
  float* x = (float*)d_out;

  char* p = (char*)d_ws;
  auto carve = [&](size_t elems) {
    bhalf* r = (bhalf*)p; p += ((elems*2 + 255) & ~(size_t)255); return r;
  };
  bhalf* wqkv_b = carve((size_t)NLAYER*QKVW*DM);   // concat(wq,wk,wv) per layer
  bhalf* wo_b = carve((size_t)NLAYER*DM*DM);
  bhalf* w1_b = carve((size_t)NLAYER*FF*DM);
  bhalf* w2_b = carve((size_t)NLAYER*DM*FF);
  bhalf* w3_b = carve((size_t)NLAYER*FF*DM);
  bhalf* hn   = carve((size_t)SLEN*DM);
  bhalf* qkv  = carve((size_t)SLEN*QKVW);
  bhalf* ab   = carve((size_t)SLEN*DM);
  bhalf* g1   = carve((size_t)SLEN*FF);

  hipMemcpyAsync(x, x_in, (size_t)SLEN*DM*sizeof(float),
                 hipMemcpyDeviceToDevice, stream);

  for (int l = 0; l < NLAYER; ++l) {
    bhalf* wb = wqkv_b + (size_t)l*QKVW*DM;
    cvt_f32_bf16<<<1024,256,0,stream>>>(wq + (size_t)l*DM*DM,  wb,                    (size_t)DM*DM);
    cvt_f32_bf16<<<512, 256,0,stream>>>(wk + (size_t)l*KVD*DM, wb + (size_t)KOFF*DM,  (size_t)KVD*DM);
    cvt_f32_bf16<<<512, 256,0,stream>>>(wv + (size_t)l*KVD*DM, wb + (size_t)VOFF*DM,  (size_t)KVD*DM);
  }
  cvt_f32_bf16<<<2048,256,0,stream>>>(wo, wo_b, (size_t)NLAYER*DM*DM);
  cvt_f32_bf16<<<2048,256,0,stream>>>(w1, w1_b, (size_t)NLAYER*FF*DM);
  cvt_f32_bf16<<<2048,256,0,stream>>>(w2, w2_b, (size_t)NLAYER*DM*FF);
  cvt_f32_bf16<<<2048,256,0,stream>>>(w3, w3_b, (size_t)NLAYER*FF*DM);

  for (int l = 0; l < NLAYER; ++l) {
    rmsnorm_k<<<SLEN,256,0,stream>>>(x, anw + l*DM, hn);
    gemm_bt<1><<<(SLEN/128)*(QKVW/128),256,0,stream>>>(
        hn, wqkv_b + (size_t)l*QKVW*DM, QKVW, DM, nullptr, nullptr, qkv);
    rope_k<<<SLEN*NH*64/256,  256,0,stream>>>(qkv, fcos, fsin, NH,   QKVW, 0);
    rope_k<<<SLEN*NKVH*64/256,256,0,stream>>>(qkv, fcos, fsin, NKVH, QKVW, KOFF);
    attn_k<<<NH*(SLEN/64),256,0,stream>>>(qkv, ab);
    gemm_bt<2><<<256,256,0,stream>>>(ab, wo_b + (size_t)l*DM*DM, DM, DM, nullptr, x, nullptr);
    rmsnorm_k<<<SLEN,256,0,stream>>>(x, fnw + l*DM, hn);
    gemm256<1><<<dim3((SLEN/256)*(FF/256),1),512,0,stream>>>(
        hn, w1_b + (size_t)l*FF*DM, FF, DM, DM, nullptr, nullptr, g1);
    gemm256<3><<<dim3((SLEN/256)*(FF/256),1),512,0,stream>>>(
        hn, w3_b + (size_t)l*FF*DM, FF, DM, DM, g1, nullptr, g1);
    gemm256<5><<<dim3((SLEN/256)*(DM/256),4),512,0,stream>>>(
        g1, w2_b + (size_t)l*DM*FF, DM, FF, FF/4, nullptr, x, nullptr);
  }
}